// Round 3
// baseline (352.360 us; speedup 1.0000x reference)
//
#include <hip/hip_runtime.h>
#include <math.h>

#define KD 200
#define CD 352
#define NITER 18
#define LMB 0.01f
#define NREG 13     // G columns per wave held in registers
#define NLDS 12     // G columns per wave streamed from LDS (NREG+NLDS = 25)

__device__ __forceinline__ float4 ld4(const float* p) { return *(const float4*)p; }
__device__ __forceinline__ void st4(float* p, float4 v) { *(float4*)p = v; }

// ---------------- Kernel 1: G = A A^T, R = B A^T (batched, 32x32 tiles) ----------------
// 784 blocks: ~3 blocks/CU so one block's barriers overlap another's compute.
// 2-wave blocks, 2x4 micro-tile, register prefetch of next k-chunk between barriers.
__global__ __launch_bounds__(128) void gemm_gr_kernel(
    const float* __restrict__ A, const float* __restrict__ B,
    float* __restrict__ G, float* __restrict__ R)
{
    __shared__ __align__(16) float Ms[16][36];   // [k][m], pad to 36 (2-way max on writes)
    __shared__ __align__(16) float Ns[16][36];   // [k][n]
    const int tid = threadIdx.x;
    const int z = blockIdx.z;
    const int b = z >> 1, which = z & 1;
    const float* __restrict__ Xb = (which ? B : A) + (size_t)b * KD * CD;
    const float* __restrict__ Ab = A + (size_t)b * KD * CD;
    float* __restrict__ O = (which ? R : G) + (size_t)b * KD * KD;
    const int tileM = blockIdx.y * 32;
    const int tileN = blockIdx.x * 32;

    const int lm = tid >> 2;             // 0..31 (row within tile)
    const int kq = (tid & 3) * 4;        // 0,4,8,12
    const int rowM = min(tileM + lm, KD - 1);
    const int rowN = min(tileN + lm, KD - 1);
    const float* __restrict__ Xrow = Xb + (size_t)rowM * CD;
    const float* __restrict__ Arow = Ab + (size_t)rowN * CD;

    const int ty = tid >> 3, tx = tid & 7;   // ty 0..15, tx 0..7
    const int m0 = ty * 2, n0 = tx * 4;

    float acc[2][4] = {};
    float4 vx = ld4(Xrow + kq);
    float4 va = ld4(Arow + kq);
    for (int kk = 0; kk < CD; kk += 16) {
        __syncthreads();                 // previous chunk's LDS reads done
        Ms[kq + 0][lm] = vx.x; Ms[kq + 1][lm] = vx.y;
        Ms[kq + 2][lm] = vx.z; Ms[kq + 3][lm] = vx.w;
        Ns[kq + 0][lm] = va.x; Ns[kq + 1][lm] = va.y;
        Ns[kq + 2][lm] = va.z; Ns[kq + 3][lm] = va.w;
        if (kk + 16 < CD) {              // next chunk's loads hide under FMAs
            vx = ld4(Xrow + kk + 16 + kq);
            va = ld4(Arow + kk + 16 + kq);
        }
        __syncthreads();                 // LDS writes visible
        #pragma unroll
        for (int k = 0; k < 16; ++k) {
            const float2 am = *(const float2*)&Ms[k][m0];
            const float4 an = ld4(&Ns[k][n0]);
            acc[0][0] = fmaf(am.x, an.x, acc[0][0]);
            acc[0][1] = fmaf(am.x, an.y, acc[0][1]);
            acc[0][2] = fmaf(am.x, an.z, acc[0][2]);
            acc[0][3] = fmaf(am.x, an.w, acc[0][3]);
            acc[1][0] = fmaf(am.y, an.x, acc[1][0]);
            acc[1][1] = fmaf(am.y, an.y, acc[1][1]);
            acc[1][2] = fmaf(am.y, an.z, acc[1][2]);
            acc[1][3] = fmaf(am.y, an.w, acc[1][3]);
        }
    }
    const int gn = tileN + n0;
    if (gn < KD) {
        #pragma unroll
        for (int i = 0; i < 2; ++i) {
            const int gm = tileM + m0 + i;
            if (gm < KD)
                st4(&O[(size_t)gm * KD + gn],
                    make_float4(acc[i][0], acc[i][1], acc[i][2], acc[i][3]));
        }
    }
}

// ------- Kernel 2: batched single-reduction PCG, 8 systems/block, G in regs+LDS -------
// R1/R2 POST-MORTEM: both __launch_bounds__(512,2) and amdgpu_waves_per_eu(2,2) left
// the VGPR budget at exactly 128 (512-thread block => 512/4 regs on this toolchain);
// g[25][4]=100 regs spilled ~60 to scratch (R2: WRITE_SIZE 66MB, VALUBusy 28%).
// FIX: design for <=128. Per wave: 13 G-columns in registers (52 regs) + 12 G-columns
// in a wave-private LDS region GL (written once at init, no barrier needed).
// Also: (a) readlane broadcast replaced by uniform-address ds_read_b128 of P (free
// wave broadcast; removes 200 VALU instr/iter onto the idle LDS pipe); (b) matvec
// runs in two system-half passes with float4 accumulators (acc 32->16 regs; g reused,
// per-(row,sys) column order unchanged => numerics identical).
// Budget: 52 g + 16 acc + 24 state + ~8 temps + ~15 misc ~= 115 < 128 => no spill.
// LDS: P 6.5K + GL 76.8K + PART 51.2K + WP 1K = 135.5KB < 160KB (1 block/CU).
__global__ __launch_bounds__(512) void cg_kernel(
    const float* __restrict__ G, const float* __restrict__ R,
    const float* __restrict__ ex, const float* __restrict__ ey,
    float* __restrict__ out)
{
    __shared__ __align__(16) float P[1664];            // p[c][s]=P[c*8+s], c<200,s<8
    __shared__ __align__(16) float GL[8][NLDS][200];   // [w][cs][gcol*4+rg], 76.8 KB
    __shared__ __align__(16) float PART[2][8][KD * 4]; // [syshalf][w][row*4+s'], 51.2 KB
    __shared__ __align__(16) float WP[8][32];          // [w][sys*4 + {pq,S2,S3,pad}]
    __shared__ float red8[8];

    const int tid = threadIdx.x;
    const int w = tid >> 6, l = tid & 63;
    const int blk = blockIdx.x;
    const int b = blk / 25;                // 25 blocks per batch
    const int i0 = (blk - b * 25) * 8;
    const int bK = b * KD;
    const float* __restrict__ Gb = G + (size_t)b * KD * KD;

    const bool mact = (l < 50);
    const int gcol = mact ? l : 49;        // lanes 50..63 duplicate row 49 (discarded)
    const int c0 = 25 * w;                 // this wave's 25 matvec columns

    // ---- G -> 13 cols in registers + 12 cols in wave-private LDS, ONCE.
    // g[c][rg] = G[c0+c][gcol+50*rg] (G symmetric; column access is coalesced).
    float g[NREG][4];
    {
        const float* __restrict__ gld = Gb + (size_t)c0 * KD + gcol;
        #pragma unroll
        for (int c = 0; c < NREG; ++c) {
            g[c][0] = gld[0];
            g[c][1] = gld[50];
            g[c][2] = gld[100];
            g[c][3] = gld[150];
            gld += KD;
        }
        #pragma unroll
        for (int cs = 0; cs < NLDS; ++cs) {
            st4(&GL[w][cs][gcol * 4],
                make_float4(gld[0], gld[50], gld[100], gld[150]));
            gld += KD;
        }
        // GL[w] is read only by wave w: no barrier needed, lgkmcnt ordering suffices.
    }

    // ---- scale = max(ex[b,:], ey[b,:]) ----
    float mxv = 0.f;
    if (tid < KD) mxv = fmaxf(ex[bK + tid], ey[bK + tid]);
    #pragma unroll
    for (int off = 32; off > 0; off >>= 1)
        mxv = fmaxf(mxv, __shfl_down(mxv, off, 64));
    if (l == 0) red8[w] = mxv;
    __syncthreads();
    float scale = red8[0];
    #pragma unroll
    for (int wv = 1; wv < 8; ++wv) scale = fmaxf(scale, red8[wv]);
    const float inv_scale = 1.0f / scale;

    // ---- state init: thread (r=tid>>1, sq=tid&1) owns systems sq*4..sq*4+3 ----
    const bool stid = tid < 400;
    const int r = tid >> 1, sq = tid & 1;
    float lam[4], dinv[4], rr[4], xx[4], pp[4], rz4[4];
    if (stid) {
        const float exj = ex[bK + r] * inv_scale;
        const float e1 = sqrtf(exj);
        const float gdiag = Gb[(size_t)r * KD + r];
        const float* __restrict__ Rb = R + (size_t)(bK + i0 + sq * 4) * KD + r;
        #pragma unroll
        for (int j = 0; j < 4; ++j) {
            const float eyi = ey[bK + i0 + sq * 4 + j] * inv_scale;
            const float e2 = sqrtf(eyi);
            const float dn = exj + eyi;
            const float re = e2 - e1;
            lam[j] = LMB * ((re * re + 1.f) / (dn * dn));
            dinv[j] = 1.f / (gdiag + lam[j]);
            rr[j] = Rb[(size_t)j * KD];
            pp[j] = rr[j] * dinv[j];      // p0 = z0
            xx[j] = 0.f;
        }
        st4(&P[r * 8 + sq * 4], make_float4(pp[0], pp[1], pp[2], pp[3]));
    }
    // rz0 partials (WP slot 0 of each system)
    {
        float vg[4];
        #pragma unroll
        for (int j = 0; j < 4; ++j) vg[j] = stid ? rr[j] * pp[j] : 0.f;
        #pragma unroll
        for (int off = 2; off < 64; off <<= 1)
            #pragma unroll
            for (int j = 0; j < 4; ++j) vg[j] += __shfl_xor(vg[j], off, 64);
        if (l < 2) {
            #pragma unroll
            for (int j = 0; j < 4; ++j) WP[w][(l * 4 + j) * 4] = vg[j];
        }
    }
    __syncthreads();                       // P + rz0 partials ready
    if (stid) {
        #pragma unroll
        for (int j = 0; j < 4; ++j) {
            float s = 0.f;
            #pragma unroll
            for (int w8 = 0; w8 < 8; ++w8) s += WP[w8][(sq * 4 + j) * 4];
            rz4[j] = s;
        }
    }

#define MAC4(A, gvv) \
    A.x = fmaf(gvv, p4.x, A.x); A.y = fmaf(gvv, p4.y, A.y); \
    A.z = fmaf(gvv, p4.z, A.z); A.w = fmaf(gvv, p4.w, A.w);

    // ============ single-reduction PCG main loop (3 barriers/iter) ============
    #pragma unroll 1
    for (int k = 0; k < NITER; ++k) {
        __syncthreads();                   // B1: P stable, WP consumed

        // ---- matvec: two system-half passes; p broadcast via uniform ds_read_b128 ----
        #pragma unroll
        for (int h = 0; h < 2; ++h) {
            float4 acc0 = {0,0,0,0}, acc1 = {0,0,0,0},
                   acc2 = {0,0,0,0}, acc3 = {0,0,0,0};
            #pragma unroll
            for (int c = 0; c < NREG; ++c) {
                const float4 p4 = ld4(&P[(c0 + c) * 8 + h * 4]);   // wave broadcast
                MAC4(acc0, g[c][0]);
                MAC4(acc1, g[c][1]);
                MAC4(acc2, g[c][2]);
                MAC4(acc3, g[c][3]);
            }
            #pragma unroll
            for (int cs = 0; cs < NLDS; ++cs) {
                const float4 gs = ld4(&GL[w][cs][gcol * 4]);
                const float4 p4 = ld4(&P[(c0 + NREG + cs) * 8 + h * 4]);
                MAC4(acc0, gs.x);
                MAC4(acc1, gs.y);
                MAC4(acc2, gs.z);
                MAC4(acc3, gs.w);
            }
            if (mact) {
                st4(&PART[h][w][(50 * 0 + l) * 4], acc0);
                st4(&PART[h][w][(50 * 1 + l) * 4], acc1);
                st4(&PART[h][w][(50 * 2 + l) * 4], acc2);
                st4(&PART[h][w][(50 * 3 + l) * 4], acc3);
            }
        }
        __syncthreads();                   // B2: PART ready

        // ---- combine q + ALL THREE dot partials (pq, S2, S3) in one phase ----
        float qq[4], vpq[4], vs2[4], vs3[4];
        if (stid) {
            float s0 = 0.f, s1 = 0.f, s2 = 0.f, s3 = 0.f;
            #pragma unroll
            for (int w8 = 0; w8 < 8; ++w8) {
                const float4 f = ld4(&PART[sq][w8][r * 4]);   // 2-way (lo/hi) = free
                s0 += f.x; s1 += f.y; s2 += f.z; s3 += f.w;
            }
            qq[0] = fmaf(lam[0], pp[0], s0);
            qq[1] = fmaf(lam[1], pp[1], s1);
            qq[2] = fmaf(lam[2], pp[2], s2);
            qq[3] = fmaf(lam[3], pp[3], s3);
            #pragma unroll
            for (int j = 0; j < 4; ++j) {
                vpq[j] = pp[j] * qq[j];
                vs2[j] = dinv[j] * rr[j] * qq[j];
                vs3[j] = dinv[j] * qq[j] * qq[j];
            }
        } else {
            #pragma unroll
            for (int j = 0; j < 4; ++j) { qq[j] = 0.f; vpq[j] = vs2[j] = vs3[j] = 0.f; }
        }
        #pragma unroll
        for (int off = 2; off < 64; off <<= 1) {
            #pragma unroll
            for (int j = 0; j < 4; ++j) {
                vpq[j] += __shfl_xor(vpq[j], off, 64);
                vs2[j] += __shfl_xor(vs2[j], off, 64);
                vs3[j] += __shfl_xor(vs3[j], off, 64);
            }
        }
        if (l < 2) {
            #pragma unroll
            for (int j = 0; j < 4; ++j)
                st4(&WP[w][(l * 4 + j) * 4],
                    make_float4(vpq[j], vs2[j], vs3[j], 0.f));
        }
        __syncthreads();                   // B3: dots ready (the ONLY reduction barrier)

        // ---- all-scalar alpha/beta + x, r, p updates ----
        if (stid) {
            #pragma unroll
            for (int j = 0; j < 4; ++j) {
                float pq = 0.f, S2 = 0.f, S3 = 0.f;
                #pragma unroll
                for (int w8 = 0; w8 < 8; ++w8) {
                    const float4 f = ld4(&WP[w8][(sq * 4 + j) * 4]);   // broadcast
                    pq += f.x; S2 += f.y; S3 += f.z;
                }
                const float alpha = rz4[j] / pq;
                // rz_new = rz - 2a*S2 + a^2*S3  (exact expansion of sum d*(r-aq)^2)
                const float rzn = fmaf(alpha * alpha, S3, fmaf(-2.f * alpha, S2, rz4[j]));
                const float beta = rzn / rz4[j];
                rz4[j] = rzn;
                xx[j] = fmaf(alpha, pp[j], xx[j]);
                rr[j] = fmaf(-alpha, qq[j], rr[j]);
                pp[j] = fmaf(beta, pp[j], rr[j] * dinv[j]);   // p = z + beta p
            }
            st4(&P[r * 8 + sq * 4], make_float4(pp[0], pp[1], pp[2], pp[3]));
        }
    }
#undef MAC4

    // ---- store x ----
    if (stid) {
        float* __restrict__ Ob = out + (size_t)(bK + i0 + sq * 4) * KD + r;
        #pragma unroll
        for (int j = 0; j < 4; ++j) Ob[(size_t)j * KD] = xx[j];
    }
}

extern "C" void kernel_launch(void* const* d_in, const int* in_sizes, int n_in,
                              void* d_out, int out_size, void* d_ws, size_t ws_size,
                              hipStream_t stream) {
    const float* A  = (const float*)d_in[0];
    const float* B  = (const float*)d_in[1];
    const float* ex = (const float*)d_in[2];
    const float* ey = (const float*)d_in[3];
    float* out = (float*)d_out;

    float* G = (float*)d_ws;
    float* R = G + 8 * KD * KD;

    dim3 grid1(7, 7, 16);
    gemm_gr_kernel<<<grid1, 128, 0, stream>>>(A, B, G, R);

    cg_kernel<<<200, 512, 0, stream>>>(G, R, ex, ey, out);
}

// Round 4
// 222.962 us; speedup vs baseline: 1.5804x; 1.5804x over previous
//
#include <hip/hip_runtime.h>
#include <math.h>

#define KD 200
#define CD 352
#define NITER 18
#define LMB 0.01f

__device__ __forceinline__ float4 ld4(const float* p) { return *(const float4*)p; }
__device__ __forceinline__ void st4(float* p, float4 v) { *(float4*)p = v; }
__device__ __forceinline__ float rdlane(float v, int lane) {
    return __int_as_float(__builtin_amdgcn_readlane(__float_as_int(v), lane));
}

// ---------------- Kernel 1: G = A A^T, R = B A^T (batched, 32x32 tiles, split-K) ------
// R3 analysis: 784 blocks x 2 waves = 1.5 waves/SIMD -> latency-starved. Split-K x2:
// each block reduces half of C=352 (176 = 11 chunks of 16) and accumulates into the
// ZEROED G/R via atomicAdd (exactly 2 commutative adds per element -> bit-deterministic).
// Grid (7,7,32) = 1568 blocks = 3.1 waves/SIMD.
__global__ __launch_bounds__(128) void gemm_gr_kernel(
    const float* __restrict__ A, const float* __restrict__ B,
    float* __restrict__ G, float* __restrict__ R)
{
    __shared__ __align__(16) float Ms[16][36];   // [k][m]
    __shared__ __align__(16) float Ns[16][36];   // [k][n]
    const int tid = threadIdx.x;
    const int z = blockIdx.z;
    const int kh = z & 1;                // K-half
    const int zz = z >> 1;
    const int b = zz >> 1, which = zz & 1;
    const float* __restrict__ Xb = (which ? B : A) + (size_t)b * KD * CD;
    const float* __restrict__ Ab = A + (size_t)b * KD * CD;
    float* __restrict__ O = (which ? R : G) + (size_t)b * KD * KD;
    const int tileM = blockIdx.y * 32;
    const int tileN = blockIdx.x * 32;

    const int lm = tid >> 2;             // 0..31 (row within tile)
    const int kq = (tid & 3) * 4;        // 0,4,8,12
    const int rowM = min(tileM + lm, KD - 1);
    const int rowN = min(tileN + lm, KD - 1);
    const int kbase = kh * 176;
    const float* __restrict__ Xrow = Xb + (size_t)rowM * CD + kbase;
    const float* __restrict__ Arow = Ab + (size_t)rowN * CD + kbase;

    const int ty = tid >> 3, tx = tid & 7;   // ty 0..15, tx 0..7
    const int m0 = ty * 2, n0 = tx * 4;

    float acc[2][4] = {};
    float4 vx = ld4(Xrow + kq);
    float4 va = ld4(Arow + kq);
    for (int kk = 0; kk < 176; kk += 16) {
        __syncthreads();                 // previous chunk's LDS reads done
        Ms[kq + 0][lm] = vx.x; Ms[kq + 1][lm] = vx.y;
        Ms[kq + 2][lm] = vx.z; Ms[kq + 3][lm] = vx.w;
        Ns[kq + 0][lm] = va.x; Ns[kq + 1][lm] = va.y;
        Ns[kq + 2][lm] = va.z; Ns[kq + 3][lm] = va.w;
        if (kk + 16 < 176) {             // next chunk's loads hide under FMAs
            vx = ld4(Xrow + kk + 16 + kq);
            va = ld4(Arow + kk + 16 + kq);
        }
        __syncthreads();                 // LDS writes visible
        #pragma unroll
        for (int k = 0; k < 16; ++k) {
            const float2 am = *(const float2*)&Ms[k][m0];
            const float4 an = ld4(&Ns[k][n0]);
            acc[0][0] = fmaf(am.x, an.x, acc[0][0]);
            acc[0][1] = fmaf(am.x, an.y, acc[0][1]);
            acc[0][2] = fmaf(am.x, an.z, acc[0][2]);
            acc[0][3] = fmaf(am.x, an.w, acc[0][3]);
            acc[1][0] = fmaf(am.y, an.x, acc[1][0]);
            acc[1][1] = fmaf(am.y, an.y, acc[1][1]);
            acc[1][2] = fmaf(am.y, an.z, acc[1][2]);
            acc[1][3] = fmaf(am.y, an.w, acc[1][3]);
        }
    }
    const int gn = tileN + n0;
    if (gn < KD) {
        #pragma unroll
        for (int i = 0; i < 2; ++i) {
            const int gm = tileM + m0 + i;
            if (gm < KD) {
                float* __restrict__ dst = &O[(size_t)gm * KD + gn];
                atomicAdd(dst + 0, acc[i][0]);
                atomicAdd(dst + 1, acc[i][1]);
                atomicAdd(dst + 2, acc[i][2]);
                atomicAdd(dst + 3, acc[i][3]);
            }
        }
    }
}

// ------- Kernel 2: batched single-reduction PCG, 4 systems/block, 3 barriers/iter -----
// R1-R3 POST-MORTEM: every attempt to hold G persistently in registers spilled (the
// 512-thread VGPR budget is pinned at 128 on this toolchain and estimates ran low).
// This is the PROVEN 126us/56-VGPR R0 base with ONE change: the matvec's G stream is
// explicitly double-buffered at register level (ga/gb, 8 cols each, bounded liveness)
// -- prefetch chunk k+1 while FMA-ing chunk k, and prefetch next ITERATION's chunk 0
// during the reduce phase (G loads are iteration-invariant: no barrier dependency).
// R0's counters (VALUBusy 38%, L2 traffic 9.1 TB/s << 34.5 ceiling) showed the G
// re-read is LATENCY-bound; this hides it. Worst-case VGPR: 56 - ~20 in-flight + 68
// buffers ~= 105 < 128. All proven sub-patterns kept: all-lane P load + COMPILE-TIME
// readlane (R9/R10/R18), exact single-reduction rz recurrence, column order unchanged
// (numerics bit-identical).
#define GLOAD8(buf, cbase) do {                                             \
    const float* __restrict__ gp_ = Gb + (size_t)(cbase) * KD + gcol;       \
    _Pragma("unroll")                                                       \
    for (int dc_ = 0; dc_ < 8; ++dc_) {                                     \
        buf[dc_][0] = gp_[0];   buf[dc_][1] = gp_[50];                      \
        buf[dc_][2] = gp_[100]; buf[dc_][3] = gp_[150];                     \
        gp_ += KD; }                                                        \
} while (0)

#define GFMA8(buf, pv) do {                                                 \
    _Pragma("unroll")                                                       \
    for (int dc_ = 0; dc_ < 8; ++dc_) {                                     \
        _Pragma("unroll")                                                   \
        for (int s_ = 0; s_ < 4; ++s_) {                                    \
            const float ps_ = rdlane(pv, dc_ * 4 + s_);                     \
            acc[0][s_] = fmaf(buf[dc_][0], ps_, acc[0][s_]);                \
            acc[1][s_] = fmaf(buf[dc_][1], ps_, acc[1][s_]);                \
            acc[2][s_] = fmaf(buf[dc_][2], ps_, acc[2][s_]);                \
            acc[3][s_] = fmaf(buf[dc_][3], ps_, acc[3][s_]); } }            \
} while (0)

__global__ __launch_bounds__(512) void cg_kernel(
    const float* __restrict__ G, const float* __restrict__ R,
    const float* __restrict__ ex, const float* __restrict__ ey,
    float* __restrict__ out)
{
    __shared__ __align__(16) float P[864];             // p[c][s]=P[c*4+s], c<200,s<4 (+pad)
    __shared__ __align__(16) float PART[8 * KD * 4];   // [w][row][s], 25.6 KB
    __shared__ __align__(16) float WP[8][16];          // [w][sys*4 + {pq,S2,S3,pad}]
    __shared__ float red8[8];

    const int tid = threadIdx.x;
    const int w = tid >> 6, l = tid & 63;
    const int blk = blockIdx.x;
    const int b = blk / 50;                // 50 blocks per batch
    const int i0 = (blk - b * 50) * 4;
    const int bK = b * KD;
    const float* __restrict__ Gb = G + (size_t)b * KD * KD;

    const bool mact = (l < 50);
    const int gcol = mact ? l : 49;        // lanes 50..63 duplicate row-group 49 (discarded)
    const int c0 = 25 * w;                 // this wave's 25 matvec columns

    // ---- prefetch iter-0 chunk 0 of G; latency hides under scale/state init ----
    float ga[8][4];
    GLOAD8(ga, c0);

    // ---- scale = max(ex[b,:], ey[b,:]) ----
    float mxv = 0.f;
    if (tid < KD) mxv = fmaxf(ex[bK + tid], ey[bK + tid]);
    #pragma unroll
    for (int off = 32; off > 0; off >>= 1)
        mxv = fmaxf(mxv, __shfl_down(mxv, off, 64));
    if (l == 0) red8[w] = mxv;
    __syncthreads();
    float scale = red8[0];
    #pragma unroll
    for (int wv = 1; wv < 8; ++wv) scale = fmaxf(scale, red8[wv]);
    const float inv_scale = 1.0f / scale;

    // ---- state init (registers): thread owns (row r, systems sq*2..sq*2+1) ----
    const bool stid = tid < 400;
    const int r = tid >> 1, sq = tid & 1;
    float lam[2], dinv[2], rr[2], xx[2], pp[2], rz4[2];
    if (stid) {
        const float exj = ex[bK + r] * inv_scale;
        const float e1 = sqrtf(exj);
        const float gdiag = Gb[(size_t)r * KD + r];
        const float* __restrict__ Rb = R + (size_t)(bK + i0 + sq * 2) * KD + r;
        #pragma unroll
        for (int j = 0; j < 2; ++j) {
            const float eyi = ey[bK + i0 + sq * 2 + j] * inv_scale;
            const float e2 = sqrtf(eyi);
            const float dn = exj + eyi;
            const float re = e2 - e1;
            lam[j] = LMB * ((re * re + 1.f) / (dn * dn));
            dinv[j] = 1.f / (gdiag + lam[j]);
            rr[j] = Rb[(size_t)j * KD];
            pp[j] = rr[j] * dinv[j];      // p0 = z0
            xx[j] = 0.f;
        }
        *(float2*)&P[r * 4 + sq * 2] = make_float2(pp[0], pp[1]);
    }
    // rz0 partials (use WP slot 0)
    {
        float vg[2];
        #pragma unroll
        for (int j = 0; j < 2; ++j) vg[j] = stid ? rr[j] * pp[j] : 0.f;
        #pragma unroll
        for (int off = 2; off < 64; off <<= 1)
            #pragma unroll
            for (int j = 0; j < 2; ++j) vg[j] += __shfl_xor(vg[j], off, 64);
        if (l < 2) {
            #pragma unroll
            for (int j = 0; j < 2; ++j) WP[w][(l * 2 + j) * 4] = vg[j];
        }
    }
    __syncthreads();                       // P + rz0 partials ready
    if (stid) {
        #pragma unroll
        for (int j = 0; j < 2; ++j) {
            float s = 0.f;
            #pragma unroll
            for (int w8 = 0; w8 < 8; ++w8) s += WP[w8][(sq * 2 + j) * 4];
            rz4[j] = s;
        }
    }

    // ============ single-reduction PCG main loop (3 barriers/iter) ============
    #pragma unroll 1
    for (int k = 0; k < NITER; ++k) {
        __syncthreads();                   // B1: P stable, WP consumed

        // ---- matvec, software-pipelined: ga holds chunk0 (prefetched last iter) ----
        float acc[4][4];
        #pragma unroll
        for (int j = 0; j < 4; ++j)
            #pragma unroll
            for (int s = 0; s < 4; ++s) acc[j][s] = 0.f;

        const float pv0 = P[(c0 + 0) * 4 + l];      // ALL lanes load (readlane hazard)
        float gb_[8][4];
        GLOAD8(gb_, c0 + 8);                        // chunk1 in flight
        const float pv1 = P[(c0 + 8) * 4 + l];
        GFMA8(ga, pv0);                             // chunk0 compute (data resident)
        GLOAD8(ga, c0 + 16);                        // chunk2 in flight (ga consumed)
        const float pv2 = P[(c0 + 16) * 4 + l];
        float gt0, gt1, gt2, gt3;                   // trailing column c0+24 in flight
        {
            const float* __restrict__ gp_ = Gb + (size_t)(c0 + 24) * KD + gcol;
            gt0 = gp_[0]; gt1 = gp_[50]; gt2 = gp_[100]; gt3 = gp_[150];
        }
        const float pvt = P[(c0 + 24) * 4 + l];
        GFMA8(gb_, pv1);                            // chunk1 compute
        GFMA8(ga, pv2);                             // chunk2 compute
        #pragma unroll
        for (int s = 0; s < 4; ++s) {               // trailing column
            const float ps = rdlane(pvt, s);
            acc[0][s] = fmaf(gt0, ps, acc[0][s]);
            acc[1][s] = fmaf(gt1, ps, acc[1][s]);
            acc[2][s] = fmaf(gt2, ps, acc[2][s]);
            acc[3][s] = fmaf(gt3, ps, acc[3][s]);
        }
        if (mact) {
            #pragma unroll
            for (int j = 0; j < 4; ++j)
                st4(&PART[w * (KD * 4) + (50 * j + l) * 4],
                    make_float4(acc[j][0], acc[j][1], acc[j][2], acc[j][3]));
        }
        GLOAD8(ga, c0);                  // prefetch NEXT iter chunk0; reduce phase covers it
        __syncthreads();                   // B2: PART ready

        // ---- combine q + ALL THREE dot partials (pq, S2, S3) in one phase ----
        float qq[2], vpq[2], vs2[2], vs3[2];
        if (stid) {
            float s0 = 0.f, s1 = 0.f;
            #pragma unroll
            for (int w8 = 0; w8 < 8; ++w8) {
                const float2 f = *(const float2*)&PART[w8 * (KD * 4) + r * 4 + sq * 2];
                s0 += f.x; s1 += f.y;
            }
            qq[0] = fmaf(lam[0], pp[0], s0);
            qq[1] = fmaf(lam[1], pp[1], s1);
            #pragma unroll
            for (int j = 0; j < 2; ++j) {
                vpq[j] = pp[j] * qq[j];
                vs2[j] = dinv[j] * rr[j] * qq[j];
                vs3[j] = dinv[j] * qq[j] * qq[j];
            }
        } else {
            qq[0] = qq[1] = 0.f;
            vpq[0] = vpq[1] = vs2[0] = vs2[1] = vs3[0] = vs3[1] = 0.f;
        }
        #pragma unroll
        for (int off = 2; off < 64; off <<= 1) {
            #pragma unroll
            for (int j = 0; j < 2; ++j) {
                vpq[j] += __shfl_xor(vpq[j], off, 64);
                vs2[j] += __shfl_xor(vs2[j], off, 64);
                vs3[j] += __shfl_xor(vs3[j], off, 64);
            }
        }
        if (l < 2) {
            #pragma unroll
            for (int j = 0; j < 2; ++j)
                st4(&WP[w][(l * 2 + j) * 4],
                    make_float4(vpq[j], vs2[j], vs3[j], 0.f));
        }
        __syncthreads();                   // B3: dots ready (the ONLY reduction barrier)

        // ---- all-scalar alpha/beta + x, r, p updates ----
        if (stid) {
            #pragma unroll
            for (int j = 0; j < 2; ++j) {
                float pq = 0.f, S2 = 0.f, S3 = 0.f;
                #pragma unroll
                for (int w8 = 0; w8 < 8; ++w8) {
                    const float4 f = ld4(&WP[w8][(sq * 2 + j) * 4]);   // broadcast
                    pq += f.x; S2 += f.y; S3 += f.z;
                }
                const float alpha = rz4[j] / pq;
                // rz_new = rz - 2a*S2 + a^2*S3  (exact expansion of sum d*(r-aq)^2)
                const float rzn = fmaf(alpha * alpha, S3, fmaf(-2.f * alpha, S2, rz4[j]));
                const float beta = rzn / rz4[j];
                rz4[j] = rzn;
                xx[j] = fmaf(alpha, pp[j], xx[j]);
                rr[j] = fmaf(-alpha, qq[j], rr[j]);
                pp[j] = fmaf(beta, pp[j], rr[j] * dinv[j]);   // p = z + beta p
            }
            *(float2*)&P[r * 4 + sq * 2] = make_float2(pp[0], pp[1]);
        }
    }

    // ---- store x ----
    if (stid) {
        float* __restrict__ Ob = out + (size_t)(bK + i0 + sq * 2) * KD + r;
        Ob[0]  = xx[0];
        Ob[KD] = xx[1];
    }
}

extern "C" void kernel_launch(void* const* d_in, const int* in_sizes, int n_in,
                              void* d_out, int out_size, void* d_ws, size_t ws_size,
                              hipStream_t stream) {
    const float* A  = (const float*)d_in[0];
    const float* B  = (const float*)d_in[1];
    const float* ex = (const float*)d_in[2];
    const float* ey = (const float*)d_in[3];
    float* out = (float*)d_out;

    float* G = (float*)d_ws;
    float* R = G + 8 * KD * KD;

    // zero G and R (contiguous) for the split-K atomic accumulation
    hipMemsetAsync(d_ws, 0, (size_t)2 * 8 * KD * KD * sizeof(float), stream);

    dim3 grid1(7, 7, 32);
    gemm_gr_kernel<<<grid1, 128, 0, stream>>>(A, B, G, R);

    cg_kernel<<<400, 512, 0, stream>>>(G, R, ex, ey, out);
}